// Round 10
// baseline (294.855 us; speedup 1.0000x reference)
//
#include <hip/hip_runtime.h>
#include <math.h>

typedef __bf16 bf16x8 __attribute__((ext_vector_type(8)));
typedef float f32x4 __attribute__((ext_vector_type(4)));
typedef unsigned short u16;

constexpr int Bn  = 32;
constexpr int HWn = 56;
constexpr int En  = 192;
constexpr int SH  = 3;
constexpr int NWn = 8;
constexpr int Ln  = HWn * HWn;
constexpr int Mn  = 49;
#define NEGV (-1e9f)

#define MFMA(a, b, c) __builtin_amdgcn_mfma_f32_16x16x32_bf16((a), (b), (c), 0, 0, 0)

__device__ __forceinline__ u16 f2b(float f) {
    unsigned u = __float_as_uint(f);
    return (u16)((u + 0x7fffu + ((u >> 16) & 1u)) >> 16);
}

// row-swizzle for 384B-stride LDS tiles (bits 4..6 of byte offset)
__device__ __forceinline__ int xm384(int row) {
    return ((row & 3) << 4) | (((row >> 2) & 1) << 6);
}

// ---------------------------------------------------------------------------
// Prep: W_qkv [192][576] fp32 -> wt bf16 [c'][k], c' = comp*192 + e
//       (de-interleave: source col = e*3+comp);
//       W_out [192][192] fp32 -> wt2 bf16 transposed [c][k] (if do2)
// ---------------------------------------------------------------------------
__global__ __launch_bounds__(256) void prep_w(const float* __restrict__ wq,
                                              const float* __restrict__ wo,
                                              u16* __restrict__ wt,
                                              u16* __restrict__ wt2, int do2) {
    int i = blockIdx.x * 256 + threadIdx.x;
    if (i < 576 * 192) {
        int cp = i / 192, k = i - cp * 192;
        int comp = cp / 192, e = cp - comp * 192;
        wt[i] = f2b(wq[k * 576 + e * 3 + comp]);
    } else if (do2) {
        int i2 = i - 576 * 192;
        if (i2 < 192 * 192) {
            int c = i2 / 192, k = i2 - c * 192;
            wt2[i2] = f2b(wo[k * 192 + c]);
        }
    }
}

// ---------------------------------------------------------------------------
// Fully-fused kernel: X -> QKV -> windowed attention -> output projection.
// One block per window: grid 2048, 512 threads (8 waves), LDS 72 KB (2/CU).
// R9 change vs R8: NO LDS staging for W_qkv — B-fragments for the QKV GEMM
// are read directly from global wt (221 KB, L2/L3-resident, shared by all
// blocks), same pattern the proj phase uses for wt2. Phase 1 now has ZERO
// internal barriers (was 12); total barriers 16 -> 6. Waves free-run.
// LDS layout (bytes):
//   phase1: XS [64r][384B] @0 (24576)
//   phase2: QS [6][64][64B] @0 (overlays XS) | KS @24576 | VT [6][32][128B] @49152
//   phase2b: PL [8w][16][128B] @0 (overlays QS after Q->regs)
//   phase3: OS [64r][384B] @24576 (overlays dead KS)
// ---------------------------------------------------------------------------
template<bool USE_WT, bool USE_WT2>
__global__ __launch_bounds__(512, 2) void swin_fused(
    const float* __restrict__ x, const u16* __restrict__ wt,
    const u16* __restrict__ wt2,
    const float* __restrict__ wq_f32, const float* __restrict__ b_qkv,
    const float* __restrict__ w_out, const float* __restrict__ b_out,
    const float* __restrict__ rel_bias, float* __restrict__ out)
{
    __shared__ char lds[73728] __attribute__((aligned(128)));

    const int tid  = threadIdx.x;
    const int w    = tid >> 6;
    const int lane = tid & 63;
    const int lq   = lane & 15;
    const int g    = lane >> 4;

    const int blk = blockIdx.x;
    const int wx = blk & 7, wy = (blk >> 3) & 7, b = blk >> 6;

    // ---- phase 0: X window -> XS (bf16, swizzled); pad rows 49..63 zeroed
    for (int j = tid; j < 64 * 48; j += 512) {
        int m = j / 48, q = j - 48 * m;
        u16 v[4];
        if (m < Mn) {
            int rr = m / 7, cc = m - 7 * rr;
            int oi = (wy * 7 + rr + SH) % HWn;
            int oj = (wx * 7 + cc + SH) % HWn;
            const float4 f = *(const float4*)(x + ((size_t)((b * HWn + oi) * HWn + oj)) * En + 4 * q);
            v[0] = f2b(f.x); v[1] = f2b(f.y); v[2] = f2b(f.z); v[3] = f2b(f.w);
        } else { v[0] = v[1] = v[2] = v[3] = 0; }
        *(ushort4*)(lds + m * 384 + ((8 * q) ^ xm384(m))) = *(ushort4*)v;
    }
    __syncthreads();                       // XS ready (the ONLY phase-1 barrier)

    // ---- phase 1: QKV = X @ W  (M=64, N=576, K=192; 6 k-tiles of 32)
    // B-fragments straight from global wt (L2-hot); no LDS, no barriers.
    f32x4 acc[4][5];
    const f32x4 zero4 = {0.f, 0.f, 0.f, 0.f};
    #pragma unroll
    for (int mf = 0; mf < 4; mf++)
        #pragma unroll
        for (int j = 0; j < 5; j++) acc[mf][j] = zero4;

    for (int kt = 0; kt < 6; kt++) {
        bf16x8 af[4];
        #pragma unroll
        for (int mf = 0; mf < 4; mf++) {
            int m = 16 * mf + lq;
            af[mf] = *(const bf16x8*)(lds + m * 384 + ((64 * kt + 16 * g) ^ xm384(m)));
        }
        #pragma unroll
        for (int j = 0; j < 5; j++) {
            int nf = w + 8 * j;
            if (nf < 36) {
                int c = 16 * nf + lq;
                bf16x8 bfr;
                if (USE_WT) {
                    bfr = *(const bf16x8*)(wt + c * 192 + kt * 32 + 8 * g);
                } else {
                    int comp = c / 192, e = c - comp * 192;
                    int col = e * 3 + comp;
                    union { bf16x8 v; u16 a[8]; } t;
                    #pragma unroll
                    for (int p = 0; p < 8; p++)
                        t.a[p] = f2b(wq_f32[(size_t)(kt * 32 + 8 * g + p) * 576 + col]);
                    bfr = t.v;
                }
                #pragma unroll
                for (int mf = 0; mf < 4; mf++)
                    acc[mf][j] = MFMA(af[mf], bfr, acc[mf][j]);
            }
        }
    }
    __syncthreads();                       // all waves done reading XS

    // ---- scatter C frags (+bias, Q scale) -> QS/KS/VT (bf16, swizzled)
    const float qscale = 0.17677669529663687f;  // 1/sqrt(32)
    #pragma unroll
    for (int j = 0; j < 5; j++) {
        int nf = w + 8 * j;
        if (nf >= 36) continue;
        int comp = nf / 12;
        int e = (nf - comp * 12) * 16 + lq;
        float bcol = b_qkv[e * 3 + comp];
        int h = e >> 5, d = e & 31;
        #pragma unroll
        for (int mf = 0; mf < 4; mf++) {
            #pragma unroll
            for (int r = 0; r < 4; r++) {
                int m = 16 * mf + 4 * g + r;
                float v = acc[mf][j][r] + bcol;
                int byte;
                if (comp == 0) { v *= qscale; byte = h * 4096 + m * 64 + ((2 * d) ^ (((m >> 1) & 3) << 4)); }
                else if (comp == 1) { byte = 24576 + h * 4096 + m * 64 + ((2 * d) ^ (((m >> 1) & 3) << 4)); }
                else { byte = 49152 + h * 4096 + d * 128 + ((2 * m) ^ ((d & 7) << 4)); }
                *(u16*)(lds + byte) = f2b(v);
            }
        }
    }
    __syncthreads();

    // ---- phase 2 setup: wave = (token block tb, head group hg)
    const int tb = w & 3, hg = w >> 2;
    const int t = 16 * tb + lq;            // this lane's token (softmax row)
    bf16x8 qreg[3];
    #pragma unroll
    for (int hh = 0; hh < 3; hh++) {
        int h = hg * 3 + hh;
        int m = 16 * tb + lq;
        qreg[hh] = *(const bf16x8*)(lds + h * 4096 + m * 64 + ((16 * g) ^ (((m >> 1) & 3) << 4)));
    }
    const bool lastR = (wy == 7), lastC = (wx == 7);
    float bias[4][4];
    #pragma unroll
    for (int mi = 0; mi < 4; mi++)
        #pragma unroll
        for (int r = 0; r < 4; r++) {
            int key = 16 * mi + 4 * g + r;
            float bv;
            if (t < Mn) {
                if (key < Mn) {
                    bv = rel_bias[t * 49 + key];
                    if (lastR && ((t >= 28) != (key >= 28))) bv += NEGV;
                    if (lastC && ((t % 7 >= 4) != (key % 7 >= 4))) bv += NEGV;
                } else bv = NEGV;          // pad keys: exp -> 0
            } else bv = 0.f;               // pad tokens: keep finite
            bias[mi][r] = bv;
        }
    __syncthreads();                       // Q in regs; PL may overlay QS

    // ---- per-head attention; keep O frags in regs (oacc[3][2])
    f32x4 oacc[3][2];
    #pragma unroll
    for (int hh = 0; hh < 3; hh++) {
        int h = hg * 3 + hh;
        f32x4 st[4];
        #pragma unroll
        for (int mi = 0; mi < 4; mi++) {
            int key = 16 * mi + lq;
            bf16x8 kf = *(const bf16x8*)(lds + 24576 + h * 4096 + key * 64 + ((16 * g) ^ (((key >> 1) & 3) << 4)));
            st[mi] = MFMA(kf, qreg[hh], zero4);
        }
        float mx = -3.4e38f;
        #pragma unroll
        for (int mi = 0; mi < 4; mi++)
            #pragma unroll
            for (int r = 0; r < 4; r++) {
                st[mi][r] += bias[mi][r];
                mx = fmaxf(mx, st[mi][r]);
            }
        mx = fmaxf(mx, __shfl_xor(mx, 16));
        mx = fmaxf(mx, __shfl_xor(mx, 32));
        float sum = 0.f;
        #pragma unroll
        for (int mi = 0; mi < 4; mi++)
            #pragma unroll
            for (int r = 0; r < 4; r++) {
                float e = __expf(st[mi][r] - mx);
                st[mi][r] = e; sum += e;
            }
        sum += __shfl_xor(sum, 16);
        sum += __shfl_xor(sum, 32);
        float inv = 1.f / sum;
        #pragma unroll
        for (int mi = 0; mi < 4; mi++)
            #pragma unroll
            for (int r = 0; r < 4; r++) {
                int key = 16 * mi + 4 * g + r;
                *(u16*)(lds + w * 2048 + lq * 128 + ((2 * key) ^ ((lq & 7) << 4))) = f2b(st[mi][r] * inv);
            }
        // O = P . V   (K = 64 keys = 2 k-tiles of 32)
        f32x4 o0 = zero4, o1 = zero4;
        #pragma unroll
        for (int kf2 = 0; kf2 < 2; kf2++) {
            bf16x8 pf = *(const bf16x8*)(lds + w * 2048 + lq * 128 + ((64 * kf2 + 16 * g) ^ ((lq & 7) << 4)));
            int d0 = lq, d1 = 16 + lq;
            bf16x8 v0 = *(const bf16x8*)(lds + 49152 + h * 4096 + d0 * 128 + ((64 * kf2 + 16 * g) ^ ((d0 & 7) << 4)));
            bf16x8 v1 = *(const bf16x8*)(lds + 49152 + h * 4096 + d1 * 128 + ((64 * kf2 + 16 * g) ^ ((d1 & 7) << 4)));
            o0 = MFMA(pf, v0, o0);
            o1 = MFMA(pf, v1, o1);
        }
        oacc[hh][0] = o0;
        oacc[hh][1] = o1;
    }

    // ---- phase 3: output projection, fused.
    // OS [64 tok][192 ch] bf16 @24576 (overlays KS; all KS reads done above).
    __syncthreads();
    #pragma unroll
    for (int hh = 0; hh < 3; hh++) {
        int h = hg * 3 + hh;
        #pragma unroll
        for (int r = 0; r < 4; r++) {
            int tk = 16 * tb + 4 * g + r;
            int c0 = h * 32 + lq;
            *(u16*)(lds + 24576 + tk * 384 + ((2 * c0) ^ xm384(tk)))        = f2b(oacc[hh][0][r]);
            *(u16*)(lds + 24576 + tk * 384 + ((2 * (c0 + 16)) ^ xm384(tk))) = f2b(oacc[hh][1][r]);
        }
    }
    __syncthreads();

    // proj GEMM: M=64 (4 mf), N=192 (12 nf), K=192 (6 kt); waves 2m x 4n.
    const int wm = w >> 2, wn = w & 3;
    f32x4 pacc[2][3];
    #pragma unroll
    for (int mi = 0; mi < 2; mi++)
        #pragma unroll
        for (int nj = 0; nj < 3; nj++) {
            float bj = b_out[16 * (3 * wn + nj) + lq];
            pacc[mi][nj] = (f32x4){bj, bj, bj, bj};
        }
    #pragma unroll
    for (int kt = 0; kt < 6; kt++) {
        bf16x8 paf[2];
        #pragma unroll
        for (int mi = 0; mi < 2; mi++) {
            int row = 16 * (2 * wm + mi) + lq;
            paf[mi] = *(const bf16x8*)(lds + 24576 + row * 384 + ((64 * kt + 16 * g) ^ xm384(row)));
        }
        #pragma unroll
        for (int nj = 0; nj < 3; nj++) {
            int c = 16 * (3 * wn + nj) + lq;
            bf16x8 pbf;
            if (USE_WT2) {
                pbf = *(const bf16x8*)(wt2 + c * 192 + kt * 32 + 8 * g);
            } else {
                union { bf16x8 v; u16 a[8]; } tt;
                #pragma unroll
                for (int p = 0; p < 8; p++)
                    tt.a[p] = f2b(w_out[(kt * 32 + 8 * g + p) * 192 + c]);
                pbf = tt.v;
            }
            #pragma unroll
            for (int mi = 0; mi < 2; mi++)
                pacc[mi][nj] = MFMA(paf[mi], pbf, pacc[mi][nj]);
        }
    }
    // epilogue: scatter final fp32 rows to un-rolled positions
    #pragma unroll
    for (int mi = 0; mi < 2; mi++)
        #pragma unroll
        for (int r = 0; r < 4; r++) {
            int tok = 16 * (2 * wm + mi) + 4 * g + r;
            if (tok < Mn) {
                int rr = tok / 7, cc = tok - 7 * rr;
                int oi = (wy * 7 + rr + SH) % HWn;
                int oj = (wx * 7 + cc + SH) % HWn;
                float* dst = out + ((size_t)((b * HWn + oi) * HWn + oj)) * En;
                #pragma unroll
                for (int nj = 0; nj < 3; nj++)
                    dst[16 * (3 * wn + nj) + lq] = pacc[mi][nj][r];
            }
        }
}

extern "C" void kernel_launch(void* const* d_in, const int* in_sizes, int n_in,
                              void* d_out, int out_size, void* d_ws, size_t ws_size,
                              hipStream_t stream) {
    const float* x        = (const float*)d_in[0];
    const float* w_qkv    = (const float*)d_in[1];
    const float* b_qkv    = (const float*)d_in[2];
    const float* w_out    = (const float*)d_in[3];
    const float* b_out    = (const float*)d_in[4];
    const float* rel_bias = (const float*)d_in[5];
    float* out = (float*)d_out;

    const size_t WT  = 576 * 192 * 2;                 // 221184
    const size_t WT2 = 192 * 192 * 2;                 // 73728
    char* ws = (char*)d_ws;

    const int GRID_A = Bn * NWn * NWn;                // 2048 windows

    if (ws_size >= WT + WT2) {
        u16* wt  = (u16*)ws;
        u16* wt2 = (u16*)(ws + WT);
        prep_w<<<576, 256, 0, stream>>>(w_qkv, w_out, wt, wt2, 1);
        swin_fused<true, true><<<GRID_A, 512, 0, stream>>>(
            x, wt, wt2, w_qkv, b_qkv, w_out, b_out, rel_bias, out);
    } else if (ws_size >= WT) {
        u16* wt = (u16*)ws;
        prep_w<<<432, 256, 0, stream>>>(w_qkv, w_out, wt, nullptr, 0);
        swin_fused<true, false><<<GRID_A, 512, 0, stream>>>(
            x, wt, nullptr, w_qkv, b_qkv, w_out, b_out, rel_bias, out);
    } else {
        swin_fused<false, false><<<GRID_A, 512, 0, stream>>>(
            x, nullptr, nullptr, w_qkv, b_qkv, w_out, b_out, rel_bias, out);
    }
}